// Round 20
// baseline (157.033 us; speedup 1.0000x reference)
//
#include <hip/hip_runtime.h>

// Problem constants
#define BB    128
#define CC    272
#define CPAD  288     // K padded to 9*32 (rows 272..287 zeroed in LDS)
#define TT    512
#define DD1   320
#define NT    128     // t-tile per block (nt=4 per wave: each af feeds 4 MFMAs)
#define LDC   130     // Xs row stride, bf16 (260 B): bank = (c*65 + t/2)%32 -> conflict-free

typedef float  f32x4  __attribute__((ext_vector_type(4)));
typedef __bf16 bf16x4 __attribute__((ext_vector_type(4)));
typedef __bf16 bf16x8 __attribute__((ext_vector_type(8)));

// lgkm-only barrier: orders LDS ops without draining vmcnt.
#define BAR() asm volatile("s_waitcnt lgkmcnt(0)\ns_barrier" ::: "memory")

// ---- prepass: W f32 -> bf16 into workspace
__global__ __launch_bounds__(256)
void w_cvt(const float* __restrict__ W, __bf16* __restrict__ Wb) {
    const int i = blockIdx.x * 256 + threadIdx.x;      // 87040 threads
    const float4* src = (const float4*)W;
    const float4 a = src[2 * i];
    const float4 b = src[2 * i + 1];
    bf16x8 h = {(__bf16)a.x, (__bf16)a.y, (__bf16)a.z, (__bf16)a.w,
                (__bf16)b.x, (__bf16)b.y, (__bf16)b.z, (__bf16)b.w};
    *(bf16x8*)(Wb + 8 * i) = h;
}

// out[b,d,t] = sum_c W[s_b,d,c] * X[b,c,t]
// 512 blocks (1D, XCD-chunked), 512 thr / 8 waves as 4(m) x 2(n), nt=4.
// MT=320 merge of the R17/R19 winner: one block covers ALL d for its (b,T0).
// Chain-model ledger vs R19: staging totals HALVE (X tile staged once, not
// once per d-half), per-CU contexts DOUBLE (2 blocks x 8 waves = 16 waves/CU),
// af/MFMA/wave totals invariant. R11 proved this geometry correct but ran it
// under (512,4) -> 64-VGPR cap -> pipeline flattened to load->use serial.
// (512,2) caps at 128 VGPRs; the kernel needs ~104 (R17-measured) -> fits.
// XCD decode: orig=(bid&7)*64+(bid>>3); b=orig>>2, T0=(orig&3)*NT. Bijective.
template <bool WB16>
__global__ __launch_bounds__(512, 2)
void subj_conv_fat(const float*  __restrict__ X,
                   const int*    __restrict__ sidx,
                   const float*  __restrict__ W,
                   const __bf16* __restrict__ Wbf,
                   float*        __restrict__ out) {
    const int bid  = blockIdx.x;                 // 0..511
    const int orig = (bid & 7) * 64 + (bid >> 3);
    const int b    = orig >> 2;
    const int T0   = (orig & 3) * NT;
    const int s    = sidx[b];

    __shared__ __align__(16) __bf16 Xs[CPAD * LDC];   // 74,880 B

    const int tid  = threadIdx.x;
    const int lane = tid & 63;
    const int wv   = tid >> 6;        // 0..7
    const int wm   = wv & 3;          // m-quarter (80 rows; 4*80 = 320) [R11-verified]
    const int wn   = wv >> 2;         // n-half (64 t)
    const int quad = lane >> 4;
    const int l16  = lane & 15;

    // ---- stage full-K X tile: 288 c x 128 t with 512 thr; 18 passes of
    // 16 rows, batched 9 (two vmcnt waits on the cold path).
    {
        const float* Xb = X + (size_t)b * CC * TT + T0;
        const int xr = tid >> 5;              // 0..15
        const int xt = (tid & 31) * 4;        // 0..124
#pragma unroll
        for (int g = 0; g < 2; ++g) {
            float4 v[9];
#pragma unroll
            for (int q = 0; q < 9; ++q) {
                const int c = xr + 16 * (g * 9 + q);
                v[q] = make_float4(0.f, 0.f, 0.f, 0.f);
                if (c < CC) v[q] = *(const float4*)(Xb + (size_t)c * TT + xt);
            }
#pragma unroll
            for (int q = 0; q < 9; ++q) {
                const int c = xr + 16 * (g * 9 + q);
                bf16x4 h = {(__bf16)v[q].x, (__bf16)v[q].y,
                            (__bf16)v[q].z, (__bf16)v[q].w};
                *(bf16x4*)&Xs[c * LDC + xt] = h;
            }
        }
    }

    // per-lane W fragment base: d-row = wm*80+mt*16+l16, k-octet = quad*8
    const size_t wrow = ((size_t)s * DD1 + wm * 80 + l16) * CC + quad * 8;
    const __bf16* Wp16 = Wbf + (WB16 ? wrow : 0);
    const float*  Wp32 = W   + (WB16 ? 0 : wrow);

    auto load_af = [&](int mt, int kc) -> bf16x8 {   // caller guarantees liveness
        const int off = mt * 16 * CC + kc * 32;
        if constexpr (WB16) {
            return *(const bf16x8*)(Wp16 + off);
        } else {
            const float4 u0 = *(const float4*)(Wp32 + off);
            const float4 u1 = *(const float4*)(Wp32 + off + 4);
            return bf16x8{(__bf16)u0.x, (__bf16)u0.y, (__bf16)u0.z, (__bf16)u0.w,
                          (__bf16)u1.x, (__bf16)u1.y, (__bf16)u1.z, (__bf16)u1.w};
        }
    };

    bf16x8 af[2][5];          // two named sets; all indices compile-time (full unroll)
    bf16x8 bfr[2][4];

    // prologue: af for kc=0,1 issued BEFORE the barrier (lgkm-only -> stay in flight)
#pragma unroll
    for (int mt = 0; mt < 5; ++mt) af[0][mt] = load_af(mt, 0);
#pragma unroll
    for (int mt = 0; mt < 5; ++mt) af[1][mt] = load_af(mt, 1);
    BAR();

    const int tcb = wn * 64 + l16;        // base t column; frags at tcb + nt*16
    // b frags for kc=0
#pragma unroll
    for (int nt = 0; nt < 4; ++nt)
#pragma unroll
        for (int j = 0; j < 8; ++j)
            bfr[0][nt][j] = Xs[(quad * 8 + j) * LDC + tcb + nt * 16];

    f32x4 acc[5][4];
#pragma unroll
    for (int mt = 0; mt < 5; ++mt)
#pragma unroll
        for (int nt = 0; nt < 4; ++nt)
            acc[mt][nt] = (f32x4){0.f, 0.f, 0.f, 0.f};

#pragma unroll
    for (int kc = 0; kc < 9; ++kc) {
        const int cur = kc & 1;
        const int nx  = cur ^ 1;
        // depth-1 LDS prefetch: b frags for kc+1 (consumed next body)
        if (kc + 1 < 9) {
#pragma unroll
            for (int nt = 0; nt < 4; ++nt)
#pragma unroll
                for (int j = 0; j < 8; ++j)
                    bfr[nx][nt][j] = Xs[((kc + 1) * 32 + quad * 8 + j) * LDC + tcb + nt * 16];
        }
#pragma unroll
        for (int mt = 0; mt < 5; ++mt) {
            // consume af[cur][mt] across 4 n-fragments ...
#pragma unroll
            for (int nt = 0; nt < 4; ++nt)
                acc[mt][nt] = __builtin_amdgcn_mfma_f32_16x16x32_bf16(
                    af[cur][mt], bfr[cur][nt], acc[mt][nt], 0, 0, 0);
            // ... then refill the slot with kc+2 (depth-2; lives at VGPR>=104)
            if (kc + 2 < 8) {
                af[cur][mt] = load_af(mt, kc + 2);
            } else if (kc + 2 == 8) {
                bf16x8 a = {(__bf16)0.f, (__bf16)0.f, (__bf16)0.f, (__bf16)0.f,
                            (__bf16)0.f, (__bf16)0.f, (__bf16)0.f, (__bf16)0.f};
                if (quad < 2) a = load_af(mt, 8);   // k 256..287: only quads 0,1 in-bounds
                af[cur][mt] = a;
            }
        }
    }

    // ---- epilogue (R11-verified map): D[m = quad*4 + r][n = l16]
#pragma unroll
    for (int mt = 0; mt < 5; ++mt) {
        const int d = wm * 80 + mt * 16 + quad * 4;
#pragma unroll
        for (int nt = 0; nt < 4; ++nt) {
            float* ob = out + ((size_t)b * DD1 + d) * TT + T0 + wn * 64 + nt * 16 + l16;
#pragma unroll
            for (int r = 0; r < 4; ++r)
                ob[(size_t)r * TT] = acc[mt][nt][r];
        }
    }
}

extern "C" void kernel_launch(void* const* d_in, const int* in_sizes, int n_in,
                              void* d_out, int out_size, void* d_ws, size_t ws_size,
                              hipStream_t stream) {
    const float* X    = (const float*)d_in[0];   // [B, C, T]
    const int*   sidx = (const int*)  d_in[1];   // [B]
    const float* W    = (const float*)d_in[2];   // [S, D1, C]
    float*       out  = (float*)d_out;           // [B, D1, T]

    dim3 grid(BB * (TT / NT));   // 512 blocks, XCD-chunked decode in-kernel
    dim3 block(512);

    const size_t need = (size_t)8 * DD1 * CC * sizeof(__bf16);   // 1,392,640 B
    if (d_ws && ws_size >= need) {
        __bf16* Wb = (__bf16*)d_ws;
        w_cvt<<<dim3(340), dim3(256), 0, stream>>>(W, Wb);
        subj_conv_fat<true><<<grid, block, 0, stream>>>(X, sidx, W, Wb, out);
    } else {
        subj_conv_fat<false><<<grid, block, 0, stream>>>(X, sidx, W, nullptr, out);
    }
}